// Round 16
// baseline (456.796 us; speedup 1.0000x reference)
//
#include <hip/hip_runtime.h>
#include <cstdint>

// CrossViewBlockTransformer on MI355X (gfx950), round 16.
// SINGLE-WAVE workgroups, ZERO barriers anywhere: the clean test of the
// barrier-convoy hypothesis (R15's test was invalidated by gload_lds4).
//   - WG = 64 threads = 1 wave, one 4x4 block per iteration, 8 blocks/WG.
//   - Xq: 4x gload_lds16 into wave-private ping-pong LDS (stride-272 chunks;
//     extraction ds_reads are 2-way bank = free). Proven path (R6/R10).
//   - Xr: 16 per-lane register loads (R10-proven; exposed latency proven
//     non-binding). NO gload_lds4 anywhere.
//   - All LDS is wave-private: intra-wave lgkmcnt ordering suffices; the
//     kernel contains no s_barrier / __syncthreads at all.
//   - 9.6KB LDS + ~128 VGPR -> 16 fully independent waves/CU; grid 4096 WGs
//     x 8 blocks = exact full residency, zero tail.
// Arithmetic identical to R14 (absmax 0.1484375).

typedef float  f4    __attribute__((ext_vector_type(4)));
typedef float  f32x4 __attribute__((ext_vector_type(4)));
typedef short  s16x4 __attribute__((ext_vector_type(4)));
typedef short  s16x8 __attribute__((ext_vector_type(8)));
typedef unsigned short u16;
typedef __bf16 bf16;

#define MFMA16(a,b,c) __builtin_amdgcn_mfma_f32_16x16x16bf16_1k((a),(b),(c),0,0,0)
#define MFMA32(a,b,c) __builtin_amdgcn_mfma_f32_16x16x32_bf16((a),(b),(c),0,0,0)

// DPP row_ror:N over 16-lane rows
#define DPP_ROR(x, N)                                                         \
  __builtin_bit_cast(float, __builtin_amdgcn_mov_dpp(                         \
      __builtin_bit_cast(int, (x)), 0x120 + (N), 0xF, 0xF, 1))

// slot0=Wq(K32) slot1=Wk(K32) slot2=Wv(K32) slot3=Wfc(K16); 4 x 8KB
__device__ __align__(16) u16 g_wpack[4 * 4096];

__device__ __forceinline__ u16 bfbits(float x) {
  return __builtin_bit_cast(u16, (bf16)x);
}

__device__ __forceinline__ void gload_lds16(const float* g, float* l) {
  __builtin_amdgcn_global_load_lds(
      (const __attribute__((address_space(1))) void*)g,
      (__attribute__((address_space(3))) void*)l, 16, 0, 0);
}

// K32 frag: pack[t=a*2+b][l][j0..7] = W[16a + (l&15)][32b + 8*(l>>4) + j]
// K16 frag: pack[t=a*4+b][l][j0..3] = W[16a + (l&15)][16b + 4*(l>>4) + j]
__global__ void prep_w(const float* __restrict__ Wq, const float* __restrict__ Wk,
                       const float* __restrict__ Wv, const float* __restrict__ Wfc)
{
  const int t = threadIdx.x;  // 256 threads
  const float* Wm[3] = {Wq, Wk, Wv};
#pragma unroll
  for (int s = 0; s < 3; ++s) {
    const float* W = Wm[s];
    for (int e = t; e < 512; e += 256) {
      const int tile = e >> 6, l = e & 63;
      const int row = 16 * (tile >> 1) + (l & 15);
      const int col = 32 * (tile & 1) + 8 * (l >> 4);
#pragma unroll
      for (int j = 0; j < 8; ++j)
        g_wpack[s * 4096 + e * 8 + j] = bfbits(W[row * 64 + col + j]);
    }
  }
  for (int e = t; e < 1024; e += 256) {
    const int tile = e >> 6, l = e & 63;
    const int row = 16 * (tile >> 2) + (l & 15);
    const int col = 16 * (tile & 3) + 4 * (l >> 4);
#pragma unroll
    for (int j = 0; j < 4; ++j)
      g_wpack[3 * 4096 + e * 4 + j] = bfbits(Wfc[row * 64 + col + j]);
  }
}

__global__ void __launch_bounds__(64, 2)
cvbt16(const float* __restrict__ qx, const float* __restrict__ rx,
       const float* __restrict__ gw, const float* __restrict__ gb,
       float* __restrict__ out)
{
  // wave-private: Xq chunk i at [i*272 .. i*272+255]; X[c][n] at
  //   (c>>4)*272 + (c&15)*16 + n.  (272 % 32 == 16 -> 2-way banks, free)
  __shared__ __align__(16) float sQ[2][1088];  // ping-pong Xq/out (8.7KB)
  __shared__ u16   sP[320];                    // attn (0.64KB)
  __shared__ float sGn[128];                   // gamma|beta (0.5KB)

  const int lane = threadIdx.x;
  const int n = lane & 15, g = lane >> 4, rp = n >> 2, wl = n & 3;

  sGn[lane]      = gw[lane];
  sGn[64 + lane] = gb[lane];
  asm volatile("s_waitcnt lgkmcnt(0)" ::: "memory");  // wave-private visibility

  // ---- persistent weight fragments (register-resident) ----
  s16x8 Wq8[4][2], Wk8[4][2], Wv8[4][2];
  s16x4 Wf4[4][4];
#pragma unroll
  for (int a = 0; a < 4; ++a) {
#pragma unroll
    for (int c2 = 0; c2 < 2; ++c2) {
      Wq8[a][c2] = *(const s16x8*)(g_wpack + 0 * 4096 + ((a * 2 + c2) * 64 + lane) * 8);
      Wk8[a][c2] = *(const s16x8*)(g_wpack + 1 * 4096 + ((a * 2 + c2) * 64 + lane) * 8);
      Wv8[a][c2] = *(const s16x8*)(g_wpack + 2 * 4096 + ((a * 2 + c2) * 64 + lane) * 8);
    }
#pragma unroll
    for (int c4 = 0; c4 < 4; ++c4)
      Wf4[a][c4] = *(const s16x4*)(g_wpack + 3 * 4096 + ((a * 4 + c4) * 64 + lane) * 4);
  }

  // per-lane source offsets within a block
  // Xq chunk i: lane -> channel 16i + (lane>>2), row lane&3, 16B (4 pixels)
  const uint32_t vq = (uint32_t)(lane >> 2) * 65536u + (uint32_t)(lane & 3) * 256u;
  // Xr: lane -> pixel (rp, wl) of channels 32kt + 8g + j
  const uint32_t vr = (uint32_t)g * 524288u + (uint32_t)rp * 256u + (uint32_t)wl;

  // XCD-contiguous swizzle over 4096 = 8 * 512 WGs; 8 consecutive blocks/WG
  const int bid = blockIdx.x;
  const int wid = (bid & 7) * 512 + (bid >> 3);
  const int nb0 = wid * 8;

  auto bbase = [](int nb) -> uint32_t {
    return ((uint32_t)nb >> 12) * 4194304u + (((uint32_t)nb >> 6) & 63) * 1024u +
           ((uint32_t)nb & 63) * 4u;
  };

  // ---- prologue: block-0 Xq loads, full drain ----
  uint32_t bb = bbase(nb0);
#pragma unroll
  for (int i = 0; i < 4; ++i)
    gload_lds16(qx + bb + vq + (uint32_t)i * 1048576u, &sQ[0][i * 272]);
  asm volatile("s_waitcnt vmcnt(0)" ::: "memory");

  const f32x4 zero = {0.f, 0.f, 0.f, 0.f};

#pragma unroll 1
  for (int t = 0; t < 8; ++t) {
    const uint32_t nbb = bbase(nb0 + (t < 7 ? t + 1 : t));
    float* qc = &sQ[t & 1][0];
    float* qn = &sQ[(t & 1) ^ 1][0];

    // gate: Xq(t) staged (the 4 stores of t-1 are the youngest VMEM)
    asm volatile("s_waitcnt vmcnt(4)" ::: "memory");
    __builtin_amdgcn_sched_barrier(0);

    // ---- issue Xr(t) per-lane loads (consumed mid-iteration) ----
    float xr[2][8];
#pragma unroll
    for (int kt = 0; kt < 2; ++kt)
#pragma unroll
      for (int j = 0; j < 8; ++j)
        xr[kt][j] = rx[bb + vr + (uint32_t)(32 * kt + j) * 65536u];
    __builtin_amdgcn_sched_barrier(0);

    // ---- issue Xq(t+1) prefetch into the other buffer ----
    if (t < 7) {
#pragma unroll
      for (int i = 0; i < 4; ++i)
        gload_lds16(qx + nbb + vq + (uint32_t)i * 1048576u, &qn[i * 272]);
    }
    __builtin_amdgcn_sched_barrier(0);

    // ---- Xq extract (own LDS, 2-way banks) + q projection ----
    s16x8 fqh[2], fql[2];
#pragma unroll
    for (int kt = 0; kt < 2; ++kt)
#pragma unroll
      for (int j = 0; j < 8; ++j) {
        const int c = 32 * kt + 8 * g + j;
        float x1 = qc[(c >> 4) * 272 + (c & 15) * 16 + n];
        bf16 h = (bf16)x1;
        fqh[kt][j] = (short)__builtin_bit_cast(u16, h);
        fql[kt][j] = (short)bfbits(x1 - (float)h);
      }
    f32x4 aq[4];
#pragma unroll
    for (int mt = 0; mt < 4; ++mt) {
      aq[mt] = zero;
#pragma unroll
      for (int kt = 0; kt < 2; ++kt) {
        aq[mt] = MFMA32(Wq8[mt][kt], fqh[kt], aq[mt]);
        aq[mt] = MFMA32(Wq8[mt][kt], fql[kt], aq[mt]);
      }
    }

    // ---- Xr cvt + k,v projections ----
    s16x8 frh[2], frl[2];
#pragma unroll
    for (int kt = 0; kt < 2; ++kt)
#pragma unroll
      for (int j = 0; j < 8; ++j) {
        float x2 = xr[kt][j];
        bf16 h = (bf16)x2;
        frh[kt][j] = (short)__builtin_bit_cast(u16, h);
        frl[kt][j] = (short)bfbits(x2 - (float)h);
      }
    f32x4 ak[4], av[4];
#pragma unroll
    for (int mt = 0; mt < 4; ++mt) { ak[mt] = zero; av[mt] = zero; }
#pragma unroll
    for (int mt = 0; mt < 4; ++mt)
#pragma unroll
      for (int kt = 0; kt < 2; ++kt) {
        ak[mt] = MFMA32(Wk8[mt][kt], frh[kt], ak[mt]);
        ak[mt] = MFMA32(Wk8[mt][kt], frl[kt], ak[mt]);
      }
#pragma unroll
    for (int nt2 = 0; nt2 < 4; ++nt2)
#pragma unroll
      for (int kt = 0; kt < 2; ++kt)
        av[nt2] = MFMA32(frh[kt], Wv8[nt2][kt], av[nt2]);

    // ---- split q,k accumulators (energy frags, same lane) ----
    s16x4 qh[4], ql[4], kh[4], kl[4];
#pragma unroll
    for (int kt = 0; kt < 4; ++kt)
#pragma unroll
      for (int r = 0; r < 4; ++r) {
        bf16 h = (bf16)aq[kt][r];
        qh[kt][r] = (short)__builtin_bit_cast(u16, h);
        ql[kt][r] = (short)bfbits(aq[kt][r] - (float)h);
        bf16 h2 = (bf16)ak[kt][r];
        kh[kt][r] = (short)__builtin_bit_cast(u16, h2);
        kl[kt][r] = (short)bfbits(ak[kt][r] - (float)h2);
      }

    // ---- energy = q^T k : 3 independent chains ----
    f32x4 e0 = zero, e1 = zero, e2 = zero;
#pragma unroll
    for (int kt = 0; kt < 4; ++kt) {
      e0 = MFMA16(qh[kt], kh[kt], e0);
      e1 = MFMA16(qh[kt], kl[kt], e1);
      e2 = MFMA16(ql[kt], kh[kt], e2);
    }

    // ---- softmax over refpix (DPP row butterflies) ----
#pragma unroll
    for (int r = 0; r < 4; ++r) {
      float x = (e0[r] + e1[r]) + e2[r];
      float m = x;
      m = fmaxf(m, DPP_ROR(m, 8));
      m = fmaxf(m, DPP_ROR(m, 4));
      m = fmaxf(m, DPP_ROR(m, 2));
      m = fmaxf(m, DPP_ROR(m, 1));
      float p = __expf(x - m);
      float s = p;
      s += DPP_ROR(s, 8);
      s += DPP_ROR(s, 4);
      s += DPP_ROR(s, 2);
      s += DPP_ROR(s, 1);
      sP[(4 * g + r) * 20 + n] = bfbits(p * __builtin_amdgcn_rcpf(s));
    }

    // ---- O tiles: A = v (same lane), B = attn^T (wave-private sP) ----
    s16x4 pa = *(const s16x4*)&sP[n * 20 + 4 * g];
    f32x4 ao[4];
#pragma unroll
    for (int mt = 0; mt < 4; ++mt) {
      s16x4 vb;
#pragma unroll
      for (int j = 0; j < 4; ++j) vb[j] = (short)bfbits(av[mt][j]);
      ao[mt] = MFMA16(vb, pa, zero);
    }

    // ---- x = Wfc * O (K16) ----
    s16x4 ob[4];
#pragma unroll
    for (int kt = 0; kt < 4; ++kt)
#pragma unroll
      for (int j = 0; j < 4; ++j) ob[kt][j] = (short)bfbits(ao[kt][j]);
    f32x4 xa[4];
#pragma unroll
    for (int mt = 0; mt < 4; ++mt) {
      xa[mt] = zero;
#pragma unroll
      for (int kt = 0; kt < 4; ++kt)
        xa[mt] = MFMA16(Wf4[mt][kt], ob[kt], xa[mt]);
    }

    // ---- GroupNorm over 64x16 ----
    float s1 = 0.f, s2 = 0.f;
#pragma unroll
    for (int mt = 0; mt < 4; ++mt)
#pragma unroll
      for (int r = 0; r < 4; ++r) {
        float v = xa[mt][r];
        s1 += v; s2 += v * v;
      }
    s1 += DPP_ROR(s1, 8);  s2 += DPP_ROR(s2, 8);
    s1 += DPP_ROR(s1, 4);  s2 += DPP_ROR(s2, 4);
    s1 += DPP_ROR(s1, 2);  s2 += DPP_ROR(s2, 2);
    s1 += DPP_ROR(s1, 1);  s2 += DPP_ROR(s2, 1);
    s1 += __shfl_xor(s1, 16);  s2 += __shfl_xor(s2, 16);
    s1 += __shfl_xor(s1, 32);  s2 += __shfl_xor(s2, 32);
    const float mean = s1 * (1.f / 1024.f);
    const float var  = s2 * (1.f / 1024.f) - mean * mean;
    const float rstd = rsqrtf(var + 1e-5f);

    // ---- affine + exact residual: RMW own buffer ----
#pragma unroll
    for (int mt = 0; mt < 4; ++mt)
#pragma unroll
      for (int r = 0; r < 4; ++r) {
        const int row = 16 * mt + 4 * g + r;
        const int addr = mt * 272 + (4 * g + r) * 16 + n;
        qc[addr] = (xa[mt][r] - mean) * rstd * sGn[row] + sGn[64 + row] + qc[addr];
      }

    // ---- store own block (ds_read_b128 -> 16B non-temporal stores) ----
#pragma unroll
    for (int i = 0; i < 4; ++i) {
      f4 o = *(const f4*)&qc[i * 272 + lane * 4];
      __builtin_nontemporal_store(
          o, (f4*)(out + bb + vq + (uint32_t)i * 1048576u));
    }

    bb = nbb;
  }
}

extern "C" void kernel_launch(void* const* d_in, const int* in_sizes, int n_in,
                              void* d_out, int out_size, void* d_ws, size_t ws_size,
                              hipStream_t stream) {
  const float* qx  = (const float*)d_in[0];
  const float* rx  = (const float*)d_in[1];
  const float* Wq  = (const float*)d_in[2];
  const float* Wk  = (const float*)d_in[3];
  const float* Wv  = (const float*)d_in[4];
  const float* Wfc = (const float*)d_in[5];
  const float* gw  = (const float*)d_in[6];
  const float* gb  = (const float*)d_in[7];
  float* out = (float*)d_out;

  prep_w<<<dim3(1), dim3(256), 0, stream>>>(Wq, Wk, Wv, Wfc);
  // 4096 single-wave WGs x 8 blocks = 16 independent waves/CU, zero barriers
  cvbt16<<<dim3(4096), dim3(64), 0, stream>>>(qx, rx, gw, gb, out);
}

// Round 17
// 218.350 us; speedup vs baseline: 2.0920x; 2.0920x over previous
//
#include <hip/hip_runtime.h>
#include <cstdint>

// CrossViewBlockTransformer on MI355X (gfx950), round 17.
// Zero-barrier STRIP-OWNING waves: WG = 1 wave owns a strip of 4 adjacent
// blocks -- the only decomposition giving BOTH full 64B-line coalescing AND
// fully independent waves (R16 proved isolated per-block waves 4x overfetch;
// R6..R14 proved 4-wave barrier WGs plateau at ~108us with all pipes ~20%).
//   - Xq strip staged densely by the wave itself: 16x gload_lds16, lane map
//     (c=4i+(l>>4), r=(l>>2)&3, quarter=l&3) covers whole 64B lines. Chunk
//     stride 264 floats -> extraction ds_reads 2-way banks (free).
//   - 4 blocks computed sequentially from wave-private LDS (R14 arithmetic);
//     Xr per-lane register loads per block (R10-proven; L1 reuse across the
//     strip's blocks). Output RMW'd into the strip buffer (exact residual),
//     stored densely at strip end. No s_barrier / __syncthreads anywhere.
//   - ~18KB LDS -> ~8 independent waves/CU; one vmcnt(16) gate per strip.
//   - prep_w parallelized to 32 WGs (was 1 WG serialized before main kernel).
// Arithmetic identical to R14 (absmax 0.1484375).

typedef float  f4    __attribute__((ext_vector_type(4)));
typedef float  f32x4 __attribute__((ext_vector_type(4)));
typedef short  s16x4 __attribute__((ext_vector_type(4)));
typedef short  s16x8 __attribute__((ext_vector_type(8)));
typedef unsigned short u16;
typedef __bf16 bf16;

#define MFMA16(a,b,c) __builtin_amdgcn_mfma_f32_16x16x16bf16_1k((a),(b),(c),0,0,0)
#define MFMA32(a,b,c) __builtin_amdgcn_mfma_f32_16x16x32_bf16((a),(b),(c),0,0,0)

// DPP row_ror:N over 16-lane rows
#define DPP_ROR(x, N)                                                         \
  __builtin_bit_cast(float, __builtin_amdgcn_mov_dpp(                         \
      __builtin_bit_cast(int, (x)), 0x120 + (N), 0xF, 0xF, 1))

// slot0=Wq(K32) slot1=Wk(K32) slot2=Wv(K32) slot3=Wfc(K16); 4 x 8KB
__device__ __align__(16) u16 g_wpack[4 * 4096];

__device__ __forceinline__ u16 bfbits(float x) {
  return __builtin_bit_cast(u16, (bf16)x);
}

__device__ __forceinline__ void gload_lds16(const float* g, float* l) {
  __builtin_amdgcn_global_load_lds(
      (const __attribute__((address_space(1))) void*)g,
      (__attribute__((address_space(3))) void*)l, 16, 0, 0);
}

// K32 frag: pack[t=a*2+b][l][j0..7] = W[16a + (l&15)][32b + 8*(l>>4) + j]
// K16 frag: pack[t=a*4+b][l][j0..3] = W[16a + (l&15)][16b + 4*(l>>4) + j]
__global__ void prep_w(const float* __restrict__ Wq, const float* __restrict__ Wk,
                       const float* __restrict__ Wv, const float* __restrict__ Wfc)
{
  const int t = blockIdx.x * 64 + threadIdx.x;   // 32 WGs x 64 = 2048 threads
  const float* Wm[3] = {Wq, Wk, Wv};
#pragma unroll
  for (int s = 0; s < 3; ++s) {
    const float* W = Wm[s];
    if (t < 512) {
      const int tile = t >> 6, l = t & 63;
      const int row = 16 * (tile >> 1) + (l & 15);
      const int col = 32 * (tile & 1) + 8 * (l >> 4);
#pragma unroll
      for (int j = 0; j < 8; ++j)
        g_wpack[s * 4096 + t * 8 + j] = bfbits(W[row * 64 + col + j]);
    }
  }
  if (t < 1024) {
    const int tile = t >> 6, l = t & 63;
    const int row = 16 * (tile >> 2) + (l & 15);
    const int col = 16 * (tile & 3) + 4 * (l >> 4);
#pragma unroll
    for (int j = 0; j < 4; ++j)
      g_wpack[3 * 4096 + t * 4 + j] = bfbits(Wfc[row * 64 + col + j]);
  }
}

__global__ void __launch_bounds__(64, 2)
cvbt17(const float* __restrict__ qx, const float* __restrict__ rx,
       const float* __restrict__ gw, const float* __restrict__ gb,
       float* __restrict__ out)
{
  // strip buffer: chunk i (channels 4i..4i+3, all 4 rows, all 16 strip-cols)
  // at [i*264 .. i*264+255]; element (c, r, scol) at float index
  //   (c>>2)*264 + (c&3)*64 + r*16 + scol   (scol = b*4 + wl)
  __shared__ __align__(16) float sS[16 * 264 + 8];   // 16.9KB
  __shared__ u16   sP[320];                          // attn (0.64KB)
  __shared__ float sGn[128];                         // gamma|beta (0.5KB)

  const int lane = threadIdx.x;
  const int n = lane & 15, g = lane >> 4, rp = n >> 2, wl = n & 3;

  sGn[lane]      = gw[lane];
  sGn[64 + lane] = gb[lane];

  // ---- persistent weight fragments (register-resident) ----
  s16x8 Wq8[4][2], Wk8[4][2], Wv8[4][2];
  s16x4 Wf4[4][4];
#pragma unroll
  for (int a = 0; a < 4; ++a) {
#pragma unroll
    for (int c2 = 0; c2 < 2; ++c2) {
      Wq8[a][c2] = *(const s16x8*)(g_wpack + 0 * 4096 + ((a * 2 + c2) * 64 + lane) * 8);
      Wk8[a][c2] = *(const s16x8*)(g_wpack + 1 * 4096 + ((a * 2 + c2) * 64 + lane) * 8);
      Wv8[a][c2] = *(const s16x8*)(g_wpack + 2 * 4096 + ((a * 2 + c2) * 64 + lane) * 8);
    }
#pragma unroll
    for (int c4 = 0; c4 < 4; ++c4)
      Wf4[a][c4] = *(const s16x4*)(g_wpack + 3 * 4096 + ((a * 4 + c4) * 64 + lane) * 4);
  }

  // per-lane offsets
  // staging/store instr i: lane -> channel 4i+(l>>4), row (l>>2)&3, 16B quarter l&3
  const uint32_t vqs = (uint32_t)(lane >> 4) * 65536u +
                       (uint32_t)((lane >> 2) & 3) * 256u + (uint32_t)(lane & 3) * 4u;
  // Xr: lane -> pixel (rp, wl) of channels 32kt + 8g + j (block col added per block)
  const uint32_t vr = (uint32_t)g * 524288u + (uint32_t)rp * 256u + (uint32_t)wl;

  // XCD-contiguous swizzle over 2048 = 8 * 256 WGs; 4 strips per WG
  const int bid = blockIdx.x;
  const int wid = (bid & 7) * 256 + (bid >> 3);
  const int si0 = wid * 4;

  auto sbase = [](int si) -> uint32_t {
    return ((uint32_t)si >> 10) * 4194304u + (((uint32_t)si >> 4) & 63) * 1024u +
           ((uint32_t)si & 15) * 16u;
  };

  const f32x4 zero = {0.f, 0.f, 0.f, 0.f};

#pragma unroll 1
  for (int t = 0; t < 4; ++t) {
    const uint32_t sb = sbase(si0 + t);

    // ---- stage Xq strip densely: 16 x gload_lds16 (full 64B lines) ----
#pragma unroll
    for (int i = 0; i < 16; ++i)
      gload_lds16(qx + sb + vqs + (uint32_t)i * 262144u, &sS[i * 264]);

#pragma unroll 1
    for (int b = 0; b < 4; ++b) {
      // ---- issue Xr(b) per-lane loads ----
      float xr[2][8];
#pragma unroll
      for (int kt = 0; kt < 2; ++kt)
#pragma unroll
        for (int j = 0; j < 8; ++j)
          xr[kt][j] = rx[sb + (uint32_t)(4 * b) + vr + (uint32_t)(32 * kt + j) * 65536u];

      if (b == 0) {  // staging complete (the 16 Xr loads above remain in flight)
        asm volatile("s_waitcnt vmcnt(16)" ::: "memory");
        __builtin_amdgcn_sched_barrier(0);
      }

      // ---- Xq extract (2-way banks) + q projection ----
      s16x8 fqh[2], fql[2];
#pragma unroll
      for (int kt = 0; kt < 2; ++kt)
#pragma unroll
        for (int j = 0; j < 8; ++j) {
          const int c = 32 * kt + 8 * g + j;
          float x1 = sS[(c >> 2) * 264 + (c & 3) * 64 + rp * 16 + b * 4 + wl];
          bf16 h = (bf16)x1;
          fqh[kt][j] = (short)__builtin_bit_cast(u16, h);
          fql[kt][j] = (short)bfbits(x1 - (float)h);
        }
      f32x4 aq[4];
#pragma unroll
      for (int mt = 0; mt < 4; ++mt) {
        aq[mt] = zero;
#pragma unroll
        for (int kt = 0; kt < 2; ++kt) {
          aq[mt] = MFMA32(Wq8[mt][kt], fqh[kt], aq[mt]);
          aq[mt] = MFMA32(Wq8[mt][kt], fql[kt], aq[mt]);
        }
      }

      // ---- Xr cvt + k,v projections ----
      s16x8 frh[2], frl[2];
#pragma unroll
      for (int kt = 0; kt < 2; ++kt)
#pragma unroll
        for (int j = 0; j < 8; ++j) {
          float x2 = xr[kt][j];
          bf16 h = (bf16)x2;
          frh[kt][j] = (short)__builtin_bit_cast(u16, h);
          frl[kt][j] = (short)bfbits(x2 - (float)h);
        }
      f32x4 ak[4], av[4];
#pragma unroll
      for (int mt = 0; mt < 4; ++mt) { ak[mt] = zero; av[mt] = zero; }
#pragma unroll
      for (int mt = 0; mt < 4; ++mt)
#pragma unroll
        for (int kt = 0; kt < 2; ++kt) {
          ak[mt] = MFMA32(Wk8[mt][kt], frh[kt], ak[mt]);
          ak[mt] = MFMA32(Wk8[mt][kt], frl[kt], ak[mt]);
        }
#pragma unroll
      for (int nt2 = 0; nt2 < 4; ++nt2)
#pragma unroll
        for (int kt = 0; kt < 2; ++kt)
          av[nt2] = MFMA32(frh[kt], Wv8[nt2][kt], av[nt2]);

      // ---- split q,k accumulators (energy frags, same lane) ----
      s16x4 qh[4], ql[4], kh[4], kl[4];
#pragma unroll
      for (int kt = 0; kt < 4; ++kt)
#pragma unroll
        for (int r = 0; r < 4; ++r) {
          bf16 h = (bf16)aq[kt][r];
          qh[kt][r] = (short)__builtin_bit_cast(u16, h);
          ql[kt][r] = (short)bfbits(aq[kt][r] - (float)h);
          bf16 h2 = (bf16)ak[kt][r];
          kh[kt][r] = (short)__builtin_bit_cast(u16, h2);
          kl[kt][r] = (short)bfbits(ak[kt][r] - (float)h2);
        }

      // ---- energy = q^T k : 3 independent chains ----
      f32x4 e0 = zero, e1 = zero, e2 = zero;
#pragma unroll
      for (int kt = 0; kt < 4; ++kt) {
        e0 = MFMA16(qh[kt], kh[kt], e0);
        e1 = MFMA16(qh[kt], kl[kt], e1);
        e2 = MFMA16(ql[kt], kh[kt], e2);
      }

      // ---- softmax over refpix (DPP row butterflies) ----
#pragma unroll
      for (int r = 0; r < 4; ++r) {
        float x = (e0[r] + e1[r]) + e2[r];
        float m = x;
        m = fmaxf(m, DPP_ROR(m, 8));
        m = fmaxf(m, DPP_ROR(m, 4));
        m = fmaxf(m, DPP_ROR(m, 2));
        m = fmaxf(m, DPP_ROR(m, 1));
        float p = __expf(x - m);
        float s = p;
        s += DPP_ROR(s, 8);
        s += DPP_ROR(s, 4);
        s += DPP_ROR(s, 2);
        s += DPP_ROR(s, 1);
        sP[(4 * g + r) * 20 + n] = bfbits(p * __builtin_amdgcn_rcpf(s));
      }

      // ---- O tiles: A = v (same lane), B = attn^T (wave-private sP) ----
      s16x4 pa = *(const s16x4*)&sP[n * 20 + 4 * g];
      f32x4 ao[4];
#pragma unroll
      for (int mt = 0; mt < 4; ++mt) {
        s16x4 vb;
#pragma unroll
        for (int j = 0; j < 4; ++j) vb[j] = (short)bfbits(av[mt][j]);
        ao[mt] = MFMA16(vb, pa, zero);
      }

      // ---- x = Wfc * O (K16) ----
      s16x4 ob[4];
#pragma unroll
      for (int kt = 0; kt < 4; ++kt)
#pragma unroll
        for (int j = 0; j < 4; ++j) ob[kt][j] = (short)bfbits(ao[kt][j]);
      f32x4 xa[4];
#pragma unroll
      for (int mt = 0; mt < 4; ++mt) {
        xa[mt] = zero;
#pragma unroll
        for (int kt = 0; kt < 4; ++kt)
          xa[mt] = MFMA16(Wf4[mt][kt], ob[kt], xa[mt]);
      }

      // ---- GroupNorm over 64x16 ----
      float s1 = 0.f, s2 = 0.f;
#pragma unroll
      for (int mt = 0; mt < 4; ++mt)
#pragma unroll
        for (int r = 0; r < 4; ++r) {
          float v = xa[mt][r];
          s1 += v; s2 += v * v;
        }
      s1 += DPP_ROR(s1, 8);  s2 += DPP_ROR(s2, 8);
      s1 += DPP_ROR(s1, 4);  s2 += DPP_ROR(s2, 4);
      s1 += DPP_ROR(s1, 2);  s2 += DPP_ROR(s2, 2);
      s1 += DPP_ROR(s1, 1);  s2 += DPP_ROR(s2, 1);
      s1 += __shfl_xor(s1, 16);  s2 += __shfl_xor(s2, 16);
      s1 += __shfl_xor(s1, 32);  s2 += __shfl_xor(s2, 32);
      const float mean = s1 * (1.f / 1024.f);
      const float var  = s2 * (1.f / 1024.f) - mean * mean;
      const float rstd = rsqrtf(var + 1e-5f);

      // ---- affine + exact residual: RMW block-b slots of the strip buffer ----
#pragma unroll
      for (int mt = 0; mt < 4; ++mt)
#pragma unroll
        for (int r = 0; r < 4; ++r) {
          const int row = 16 * mt + 4 * g + r;
          const int addr = (row >> 2) * 264 + (row & 3) * 64 + rp * 16 + b * 4 + wl;
          sS[addr] = (xa[mt][r] - mean) * rstd * sGn[row] + sGn[64 + row] + sS[addr];
        }
    }  // blocks

    // ---- dense strip store: b128 LDS reads -> 16B non-temporal stores ----
#pragma unroll
    for (int i = 0; i < 16; ++i) {
      f4 o = *(const f4*)&sS[i * 264 + lane * 4];
      __builtin_nontemporal_store(o, (f4*)(out + sb + vqs + (uint32_t)i * 262144u));
    }
    // LDS reads above must land in VGPRs before next strip's gload_lds
    // overwrites the buffer (store issue consumes them; belt-and-suspenders):
    asm volatile("s_waitcnt lgkmcnt(0)" ::: "memory");
  }  // strips
}

extern "C" void kernel_launch(void* const* d_in, const int* in_sizes, int n_in,
                              void* d_out, int out_size, void* d_ws, size_t ws_size,
                              hipStream_t stream) {
  const float* qx  = (const float*)d_in[0];
  const float* rx  = (const float*)d_in[1];
  const float* Wq  = (const float*)d_in[2];
  const float* Wk  = (const float*)d_in[3];
  const float* Wv  = (const float*)d_in[4];
  const float* Wfc = (const float*)d_in[5];
  const float* gw  = (const float*)d_in[6];
  const float* gb  = (const float*)d_in[7];
  float* out = (float*)d_out;

  prep_w<<<dim3(32), dim3(64), 0, stream>>>(Wq, Wk, Wv, Wfc);
  // 2048 single-wave WGs x 4 strips; ~8 independent waves/CU, zero barriers
  cvbt17<<<dim3(2048), dim3(64), 0, stream>>>(qx, rx, gw, gb, out);
}